// Round 3
// baseline (241.010 us; speedup 1.0000x reference)
//
#include <hip/hip_runtime.h>

#define SQ   2048
#define HEADS 16
#define HD   64
#define EMB  1024

typedef __attribute__((ext_vector_type(2))) __fp16 h2;
typedef __attribute__((ext_vector_type(4))) __fp16 h4;
typedef __attribute__((ext_vector_type(8))) __fp16 h8;
typedef __attribute__((ext_vector_type(4))) float f4;
typedef unsigned short USH;
typedef unsigned int   UI;

__device__ __forceinline__ UI pkh(float a, float b) {   // pack 2 f16 (RTZ)
    h2 v = __builtin_amdgcn_cvt_pkrtz(a, b);
    return __builtin_bit_cast(UI, v);
}

// async global->LDS, 16B per lane; LDS dest = wave-uniform base + lane*16
__device__ __forceinline__ void glds16(const void* g, void* l) {
    __builtin_amdgcn_global_load_lds(
        (const __attribute__((address_space(1))) unsigned int*)g,
        (__attribute__((address_space(3))) unsigned int*)l, 16, 0, 0);
}

// ---------------------------------------------------------------------------
// Fused Q/K/V per-head projections (y=0,1,2) + Wo fp32->f16 cast (y=3).
// C = W * X^T (operand swap). Q/K written [n,h,s,d]; V written TRANSPOSED
// [n,h,d,s] (plain s -- the r1/r2 LDS bank swizzle is gone: attn now reads
// V direct from global). Q carries 0.125*log2(e) so softmax is bare exp2.
// Block remap (bx&7)*32+(bx>>3): XCD x owns 32 CONSECUTIVE s-chunks, so
// Vt's 64B lines (32 consecutive s = 2 adjacent chunks) are written by
// same-XCD blocks -> L2 merges the 8B partial-line V stores locally
// instead of cross-XCD partial-line HBM writes.
// ---------------------------------------------------------------------------
__global__ __launch_bounds__(256) void proj_fused(
    const float* __restrict__ q_in, const float* __restrict__ k_in,
    const float* __restrict__ v_in, const float* __restrict__ Wq,
    const float* __restrict__ Wk,   const float* __restrict__ Wv,
    const float* __restrict__ Wo,
    USH* __restrict__ Qh, USH* __restrict__ Kh, USH* __restrict__ Vt,
    USH* __restrict__ Wob)
{
    int t = threadIdx.x;
    if (blockIdx.y == 3) {
        int i = blockIdx.x * 256 + t;
        for (int j = 0; j < 4; ++j) {
            float4 v = ((const float4*)Wo)[i + j * 65536];
            uint2 pk; pk.x = pkh(v.x, v.y); pk.y = pkh(v.z, v.w);
            *(uint2*)(Wob + ((size_t)i + (size_t)j * 65536) * 4) = pk;
        }
        return;
    }
    const float* X = (blockIdx.y == 0) ? q_in : (blockIdx.y == 1) ? k_in : v_in;
    const float* W = (blockIdx.y == 0) ? Wq   : (blockIdx.y == 1) ? Wk   : Wv;
    float scale    = (blockIdx.y == 0) ? 0.18033688011112043f : 1.0f;

    // XCD-major s-chunk assignment (XCD = bx%8 heuristic)
    int bx = (blockIdx.x & 7) * 32 + (blockIdx.x >> 3);

    __shared__ __align__(16) USH Xl[256][72];
    __shared__ __align__(16) USH Wl[64][72];

    const float4* Xg = (const float4*)(X + (size_t)bx * 16384);
    for (int j = 0; j < 16; ++j) {
        int f = t + j * 256;
        float4 v = Xg[f];
        int row = f >> 4; int col = (f & 15) << 2;
        uint2 pk; pk.x = pkh(v.x, v.y); pk.y = pkh(v.z, v.w);
        *(uint2*)&Xl[row][col] = pk;
    }
    const float4* Wg = (const float4*)W;
    for (int j = 0; j < 4; ++j) {
        int f = t + j * 256;
        float4 v = Wg[f];
        int row = f >> 4; int col = (f & 15) << 2;
        uint2 pk; pk.x = pkh(v.x, v.y); pk.y = pkh(v.z, v.w);
        *(uint2*)&Wl[row][col] = pk;
    }
    __syncthreads();

    int wv = t >> 6, lane = t & 63, l4 = lane & 15, quad = lane >> 4;

    h8 wf[4][2], xf[4][2];
    for (int et = 0; et < 4; ++et)
        for (int ks = 0; ks < 2; ++ks)
            wf[et][ks] = *(const h8*)&Wl[et * 16 + l4][ks * 32 + quad * 8];
    for (int rt = 0; rt < 4; ++rt)
        for (int ks = 0; ks < 2; ++ks)
            xf[rt][ks] = *(const h8*)&Xl[wv * 64 + rt * 16 + l4][ks * 32 + quad * 8];

    f4 acc[4][4];
    for (int et = 0; et < 4; ++et)
        for (int rt = 0; rt < 4; ++rt) acc[et][rt] = (f4)(0.0f);
    for (int et = 0; et < 4; ++et)
        for (int rt = 0; rt < 4; ++rt)
            for (int ks = 0; ks < 2; ++ks)
                acc[et][rt] = __builtin_amdgcn_mfma_f32_16x16x32_f16(
                    wf[et][ks], xf[rt][ks], acc[et][rt], 0, 0, 0);

    if (blockIdx.y == 2) {
        int ns0 = bx * 16 + wv * 4;
        int n = ns0 >> 11, s = ns0 & 2047;
        for (int et = 0; et < 4; ++et)
            for (int j = 0; j < 4; ++j) {
                int e = et * 16 + quad * 4 + j;
                uint2 pk;
                pk.x = pkh(acc[et][0][j], acc[et][1][j]);
                pk.y = pkh(acc[et][2][j], acc[et][3][j]);
                *(uint2*)(Vt + (((size_t)(n * HEADS + l4) * HD + e) * SQ + s)) = pk;
            }
    } else {
        USH* Out = (blockIdx.y == 0) ? Qh : Kh;
        for (int rt = 0; rt < 4; ++rt) {
            int ns = bx * 16 + wv * 4 + rt;
            int n = ns >> 11, s = ns & 2047;
            USH* ob = Out + (((size_t)(n * HEADS) + l4) * SQ + s) * HD;
            for (int et = 0; et < 4; ++et) {
                uint2 pk;
                pk.x = pkh(acc[et][rt][0] * scale, acc[et][rt][1] * scale);
                pk.y = pkh(acc[et][rt][2] * scale, acc[et][rt][3] * scale);
                *(uint2*)(ob + et * 16 + quad * 4) = pk;
            }
        }
    }
}

// ---------------------------------------------------------------------------
// Flash attention, no-max exp2 softmax. BARRIER-FREE main loop.
// r0-r2 evidence: dur pinned at 70-72us across occupancy 21/34/36% and
// bank-conflicts 9M/17M -- the wall was the per-iter lockstep barrier
// (vmcnt0+lgkmcnt0 drain, 4 waves + 4 blocks phase-locked), not occupancy,
// not LDS banks. K/V is XCD-L2-resident (nh=b&31 -> all 32 q-tile blocks
// of a head on XCD nh%8; 4 heads x 512KB = 2MB < 4MB L2), so per catalog
// (LDS-staging L2-fit data is overhead): read K/V fragments DIRECT from
// global, register-double-buffered one tile ahead. No LDS, no syncthreads
// until the final cross-wave reduction. Waves fully desynchronized.
// Wave = 16-key stripe x all 64 q (r0 decomposition: zero intra-block
// read duplication). ~94 arch VGPR + 64 AGPR -> (256,3), no spill.
// ---------------------------------------------------------------------------
__global__ __launch_bounds__(256, 3) void attn_kernel(
    const USH* __restrict__ Qh, const USH* __restrict__ Kh,
    const USH* __restrict__ Vt, USH* __restrict__ Oh)
{
    __shared__ struct { float Osum[64][68]; float Lsum[64]; } lds;

    int t = threadIdx.x, w = t >> 6, lane = t & 63;
    int l4 = lane & 15, quad = lane >> 4;
    int b = blockIdx.x;
    int nh = b & 31;                 // all q-tiles of a head land on one XCD
    int q0 = (b >> 5) * 64;
    const USH* Qg = Qh + ((size_t)nh * SQ + q0) * HD;
    const USH* Kg = Kh + (size_t)nh * SQ * HD;
    const USH* Vg = Vt + (size_t)nh * HD * SQ;

    // Q fragments direct from global (one-time; B-operand layout)
    h8 bq[4][2];
#pragma unroll
    for (int qt = 0; qt < 4; ++qt)
#pragma unroll
        for (int ks = 0; ks < 2; ++ks)
            bq[qt][ks] = *(const h8*)(Qg + (size_t)(qt * 16 + l4) * HD + ks * 32 + quad * 8);

    f4 o[4][4];
#pragma unroll
    for (int dt = 0; dt < 4; ++dt)
#pragma unroll
        for (int qt = 0; qt < 4; ++qt) o[dt][qt] = (f4)(0.0f);
    float lsum[4] = {0.f, 0.f, 0.f, 0.f};

    // Rolling per-lane global pointers.
    // K frag (A-op 16x16x32): row key = kt*64 + w*16 + l4, 16B at d = quad*8 (+32 ks1)
    // V frag (A-op 16x16x16): row d = dt*16 + l4, 8B at key = kt*64 + w*16 + quad*4
    const USH* kp = Kg + (size_t)(w * 16 + l4) * HD + quad * 8;
    const USH* vp = Vg + (size_t)l4 * SQ + w * 16 + quad * 4;

#define ATTN_STEP(ak, av)                                                      \
    {                                                                          \
        h4 p[4];                                                               \
        _Pragma("unroll")                                                      \
        for (int qt = 0; qt < 4; ++qt) {                                       \
            f4 s0 = __builtin_amdgcn_mfma_f32_16x16x32_f16(ak[0], bq[qt][0],   \
                                                           (f4)(0.0f),0,0,0);  \
            f4 sc = __builtin_amdgcn_mfma_f32_16x16x32_f16(ak[1], bq[qt][1],   \
                                                           s0, 0, 0, 0);       \
            float p0 = __builtin_amdgcn_exp2f(sc[0]);                          \
            float p1 = __builtin_amdgcn_exp2f(sc[1]);                          \
            float p2 = __builtin_amdgcn_exp2f(sc[2]);                          \
            float p3 = __builtin_amdgcn_exp2f(sc[3]);                          \
            lsum[qt] += (p0 + p1) + (p2 + p3);                                 \
            uint2 u; u.x = pkh(p0, p1); u.y = pkh(p2, p3);                     \
            p[qt] = __builtin_bit_cast(h4, u);                                 \
        }                                                                      \
        _Pragma("unroll")                                                      \
        for (int dt = 0; dt < 4; ++dt)                                         \
            _Pragma("unroll")                                                  \
            for (int qt = 0; qt < 4; ++qt)                                     \
                o[dt][qt] = __builtin_amdgcn_mfma_f32_16x16x16f16(             \
                    av[dt], p[qt], o[dt][qt], 0, 0, 0);                        \
    }

    h8 akA[2], akB[2];
    h4 avA[4], avB[4];

    // prologue: tile 0 -> A
    akA[0] = *(const h8*)kp;  akA[1] = *(const h8*)(kp + 32);
    avA[0] = *(const h4*)vp;            avA[1] = *(const h4*)(vp + 16 * SQ);
    avA[2] = *(const h4*)(vp + 32 * SQ); avA[3] = *(const h4*)(vp + 48 * SQ);

    for (int kt = 0; kt < 32; kt += 2) {
        // issue tile kt+1 -> B (K tile stride 64*HD=4096 USH, V stride 64)
        const USH* kpB = kp + 4096;
        const USH* vpB = vp + 64;
        akB[0] = *(const h8*)kpB;  akB[1] = *(const h8*)(kpB + 32);
        avB[0] = *(const h4*)vpB;             avB[1] = *(const h4*)(vpB + 16 * SQ);
        avB[2] = *(const h4*)(vpB + 32 * SQ); avB[3] = *(const h4*)(vpB + 48 * SQ);

        ATTN_STEP(akA, avA)

        // issue tile kt+2 -> A. At kt=30 this reads one tile past this
        // head's K/V -- lands in the next workspace buffer (mapped),
        // values never used. Avoids a branch in the hot loop.
        kp += 8192; vp += 128;
        akA[0] = *(const h8*)kp;  akA[1] = *(const h8*)(kp + 32);
        avA[0] = *(const h4*)vp;             avA[1] = *(const h4*)(vp + 16 * SQ);
        avA[2] = *(const h4*)(vp + 32 * SQ); avA[3] = *(const h4*)(vp + 48 * SQ);

        ATTN_STEP(akB, avB)
    }
#undef ATTN_STEP

    // quad-reduce lsum (quads hold disjoint keys of this wave's stripe)
#pragma unroll
    for (int qt = 0; qt < 4; ++qt) {
        lsum[qt] += __shfl_xor(lsum[qt], 16, 64);
        lsum[qt] += __shfl_xor(lsum[qt], 32, 64);
    }

    // cross-wave O/L reduction through LDS (only sync in the kernel)
    __syncthreads();
    for (int ph = 0; ph < 4; ++ph) {
        if (w == ph) {
            for (int dt = 0; dt < 4; ++dt)
                for (int qt = 0; qt < 4; ++qt) {
                    float* dst = &lds.Osum[qt * 16 + l4][dt * 16 + quad * 4];
                    f4 val = o[dt][qt];
                    if (ph) val += *(const f4*)dst;
                    *(f4*)dst = val;
                }
            if (quad == 0)
                for (int qt = 0; qt < 4; ++qt) {
                    int qi = qt * 16 + l4;
                    lds.Lsum[qi] = ph ? (lds.Lsum[qi] + lsum[qt]) : lsum[qt];
                }
        }
        __syncthreads();
    }

    // epilogue: normalize + f16 store
    int n = nh >> 4, h = nh & 15;
    int q = t >> 2, d0 = (t & 3) * 16;
    float inv = 1.0f / lds.Lsum[q];
    float vv[16];
#pragma unroll
    for (int i = 0; i < 4; ++i) {
        f4 x = *(const f4*)&lds.Osum[q][d0 + i * 4];
        vv[i * 4 + 0] = x[0] * inv; vv[i * 4 + 1] = x[1] * inv;
        vv[i * 4 + 2] = x[2] * inv; vv[i * 4 + 3] = x[3] * inv;
    }
    uint4 ou0, ou1;
    ou0.x = pkh(vv[0], vv[1]);   ou0.y = pkh(vv[2], vv[3]);
    ou0.z = pkh(vv[4], vv[5]);   ou0.w = pkh(vv[6], vv[7]);
    ou1.x = pkh(vv[8], vv[9]);   ou1.y = pkh(vv[10], vv[11]);
    ou1.z = pkh(vv[12], vv[13]); ou1.w = pkh(vv[14], vv[15]);
    USH* ob = Oh + ((size_t)(n * SQ + q0 + q)) * EMB + h * HD + d0;
    *(uint4*)ob = ou0;
    *(uint4*)(ob + 8) = ou1;
}

// ---------------------------------------------------------------------------
// Output GEMM: C[4096][1024] = A[4096][1024] * B[1024][1024]^T (f16 -> fp32)
// BM=BN=64, BK=64 dbuf (32KB), grid 1024 = 4 blocks/CU, 16 waves/CU.
// m_tile = b & 63 -> XCD = m%8: per-XCD set = 8 A-slabs (1MB) + B (2MB)
// stays L2-resident; 4 desynced barrier domains/CU hide L2 latency.
// ---------------------------------------------------------------------------
__global__ __launch_bounds__(256, 4) void gemm_bt(const USH* __restrict__ A,
                                                  const USH* __restrict__ B,
                                                  float* __restrict__ C)
{
    __shared__ __align__(16) USH Al[2][4096];
    __shared__ __align__(16) USH Bl[2][4096];
    int t = threadIdx.x, w = t >> 6, lane = t & 63;
    int l4 = lane & 15, quad = lane >> 4;
    int b = blockIdx.x;
    int m0 = (b & 63) * 64;
    int n0 = (b >> 6) * 64;
    int wm = (w >> 1) * 32, wn = (w & 1) * 32;

    f4 acc[2][2];
    for (int mt = 0; mt < 2; ++mt)
        for (int nt = 0; nt < 2; ++nt) acc[mt][nt] = (f4)(0.0f);

    int aslot[2][2], bslot[2][2];
#pragma unroll
    for (int mt = 0; mt < 2; ++mt)
#pragma unroll
        for (int ks = 0; ks < 2; ++ks) {
            int m = wm + mt * 16 + l4;
            aslot[mt][ks] = m * 8 + ((ks * 4 + quad) ^ (m & 7));
            int nn = wn + mt * 16 + l4;
            bslot[mt][ks] = nn * 8 + ((ks * 4 + quad) ^ (nn & 7));
        }

    // prologue: stage ki=0 into buffer 0
#pragma unroll
    for (int j = 0; j < 2; ++j) {
        int s = (w * 2 + j) * 64 + lane;
        int r = s >> 3, c = (s & 7) ^ (r & 7);
        glds16(A + (size_t)(m0 + r) * 1024 + c * 8, Al[0] + s * 8);
        glds16(B + (size_t)(n0 + r) * 1024 + c * 8, Bl[0] + s * 8);
    }

    for (int ki = 0; ki < 16; ++ki) {
        int cur = ki & 1;
        __syncthreads();
        if (ki + 1 < 16) {
            int k0 = (ki + 1) * 64;
#pragma unroll
            for (int j = 0; j < 2; ++j) {
                int s = (w * 2 + j) * 64 + lane;
                int r = s >> 3, c = (s & 7) ^ (r & 7);
                glds16(A + (size_t)(m0 + r) * 1024 + k0 + c * 8, Al[cur ^ 1] + s * 8);
                glds16(B + (size_t)(n0 + r) * 1024 + k0 + c * 8, Bl[cur ^ 1] + s * 8);
            }
        }

        h8 a[2][2], bf[2][2];
#pragma unroll
        for (int mt = 0; mt < 2; ++mt)
#pragma unroll
            for (int ks = 0; ks < 2; ++ks) {
                a[mt][ks]  = *(const h8*)(Al[cur] + aslot[mt][ks] * 8);
                bf[mt][ks] = *(const h8*)(Bl[cur] + bslot[mt][ks] * 8);
            }
#pragma unroll
        for (int mt = 0; mt < 2; ++mt)
#pragma unroll
            for (int nt = 0; nt < 2; ++nt)
#pragma unroll
                for (int ks = 0; ks < 2; ++ks)
                    acc[mt][nt] = __builtin_amdgcn_mfma_f32_16x16x32_f16(
                        a[mt][ks], bf[nt][ks], acc[mt][nt], 0, 0, 0);
    }

    for (int mt = 0; mt < 2; ++mt)
        for (int nt = 0; nt < 2; ++nt)
            for (int r = 0; r < 4; ++r)
                C[(size_t)(m0 + wm + mt * 16 + quad * 4 + r) * 1024 +
                  (n0 + wn + nt * 16 + l4)] = acc[mt][nt][r];
}

// ---------------------------------------------------------------------------
extern "C" void kernel_launch(void* const* d_in, const int* in_sizes, int n_in,
                              void* d_out, int out_size, void* d_ws, size_t ws_size,
                              hipStream_t stream) {
    const float* k_in = (const float*)d_in[0];
    const float* q_in = (const float*)d_in[1];
    const float* v_in = (const float*)d_in[2];
    const float* Wk   = (const float*)d_in[3];
    const float* Wq   = (const float*)d_in[4];
    const float* Wv   = (const float*)d_in[5];
    const float* Wo   = (const float*)d_in[6];
    float* out = (float*)d_out;

    char* ws = (char*)d_ws;
    USH* Qh  = (USH*)(ws);               //  8 MB [n,h,s,d] f16 (scale folded)
    USH* Kh  = (USH*)(ws + 8388608);     //  8 MB [n,h,s,d]
    USH* Vt  = (USH*)(ws + 16777216);    //  8 MB [n,h,d,s]
    USH* Oh  = (USH*)(ws + 25165824);    //  8 MB [n,s,1024]
    USH* Wob = (USH*)(ws + 33554432);    //  2 MB

    proj_fused<<<dim3(256, 4), dim3(256), 0, stream>>>(
        q_in, k_in, v_in, Wq, Wk, Wv, Wo, Qh, Kh, Vt, Wob);
    attn_kernel<<<dim3(1024), dim3(256), 0, stream>>>(Qh, Kh, Vt, Oh);
    gemm_bt<<<dim3(1024), dim3(256), 0, stream>>>(Oh, Wob, out);
}

// Round 4
// 193.615 us; speedup vs baseline: 1.2448x; 1.2448x over previous
//
#include <hip/hip_runtime.h>

#define SQ   2048
#define HEADS 16
#define HD   64
#define EMB  1024

typedef __attribute__((ext_vector_type(2))) __fp16 h2;
typedef __attribute__((ext_vector_type(4))) __fp16 h4;
typedef __attribute__((ext_vector_type(8))) __fp16 h8;
typedef __attribute__((ext_vector_type(4))) float f4;
typedef unsigned short USH;
typedef unsigned int   UI;

__device__ __forceinline__ UI pkh(float a, float b) {   // pack 2 f16 (RTZ)
    h2 v = __builtin_amdgcn_cvt_pkrtz(a, b);
    return __builtin_bit_cast(UI, v);
}

// async global->LDS, 16B per lane; LDS dest = wave-uniform base + lane*16
__device__ __forceinline__ void glds16(const void* g, void* l) {
    __builtin_amdgcn_global_load_lds(
        (const __attribute__((address_space(1))) unsigned int*)g,
        (__attribute__((address_space(3))) unsigned int*)l, 16, 0, 0);
}

// ---------------------------------------------------------------------------
// Fused Q/K/V per-head projections (y=0,1,2) + Wo fp32->f16 cast (y=3).
// C = W * X^T (operand swap). Q/K written [n,h,s,d]; V written TRANSPOSED
// [n,h,d,s] (plain s). Q carries 0.125*log2(e) so softmax is bare exp2.
// Block remap (bx&7)*32+(bx>>3): XCD-major s-chunks (r3, kept).
// ---------------------------------------------------------------------------
__global__ __launch_bounds__(256) void proj_fused(
    const float* __restrict__ q_in, const float* __restrict__ k_in,
    const float* __restrict__ v_in, const float* __restrict__ Wq,
    const float* __restrict__ Wk,   const float* __restrict__ Wv,
    const float* __restrict__ Wo,
    USH* __restrict__ Qh, USH* __restrict__ Kh, USH* __restrict__ Vt,
    USH* __restrict__ Wob)
{
    int t = threadIdx.x;
    if (blockIdx.y == 3) {
        int i = blockIdx.x * 256 + t;
        for (int j = 0; j < 4; ++j) {
            float4 v = ((const float4*)Wo)[i + j * 65536];
            uint2 pk; pk.x = pkh(v.x, v.y); pk.y = pkh(v.z, v.w);
            *(uint2*)(Wob + ((size_t)i + (size_t)j * 65536) * 4) = pk;
        }
        return;
    }
    const float* X = (blockIdx.y == 0) ? q_in : (blockIdx.y == 1) ? k_in : v_in;
    const float* W = (blockIdx.y == 0) ? Wq   : (blockIdx.y == 1) ? Wk   : Wv;
    float scale    = (blockIdx.y == 0) ? 0.18033688011112043f : 1.0f;

    int bx = (blockIdx.x & 7) * 32 + (blockIdx.x >> 3);

    __shared__ __align__(16) USH Xl[256][72];
    __shared__ __align__(16) USH Wl[64][72];

    const float4* Xg = (const float4*)(X + (size_t)bx * 16384);
    for (int j = 0; j < 16; ++j) {
        int f = t + j * 256;
        float4 v = Xg[f];
        int row = f >> 4; int col = (f & 15) << 2;
        uint2 pk; pk.x = pkh(v.x, v.y); pk.y = pkh(v.z, v.w);
        *(uint2*)&Xl[row][col] = pk;
    }
    const float4* Wg = (const float4*)W;
    for (int j = 0; j < 4; ++j) {
        int f = t + j * 256;
        float4 v = Wg[f];
        int row = f >> 4; int col = (f & 15) << 2;
        uint2 pk; pk.x = pkh(v.x, v.y); pk.y = pkh(v.z, v.w);
        *(uint2*)&Wl[row][col] = pk;
    }
    __syncthreads();

    int wv = t >> 6, lane = t & 63, l4 = lane & 15, quad = lane >> 4;

    h8 wf[4][2], xf[4][2];
    for (int et = 0; et < 4; ++et)
        for (int ks = 0; ks < 2; ++ks)
            wf[et][ks] = *(const h8*)&Wl[et * 16 + l4][ks * 32 + quad * 8];
    for (int rt = 0; rt < 4; ++rt)
        for (int ks = 0; ks < 2; ++ks)
            xf[rt][ks] = *(const h8*)&Xl[wv * 64 + rt * 16 + l4][ks * 32 + quad * 8];

    f4 acc[4][4];
    for (int et = 0; et < 4; ++et)
        for (int rt = 0; rt < 4; ++rt) acc[et][rt] = (f4)(0.0f);
    for (int et = 0; et < 4; ++et)
        for (int rt = 0; rt < 4; ++rt)
            for (int ks = 0; ks < 2; ++ks)
                acc[et][rt] = __builtin_amdgcn_mfma_f32_16x16x32_f16(
                    wf[et][ks], xf[rt][ks], acc[et][rt], 0, 0, 0);

    if (blockIdx.y == 2) {
        int ns0 = bx * 16 + wv * 4;
        int n = ns0 >> 11, s = ns0 & 2047;
        for (int et = 0; et < 4; ++et)
            for (int j = 0; j < 4; ++j) {
                int e = et * 16 + quad * 4 + j;
                uint2 pk;
                pk.x = pkh(acc[et][0][j], acc[et][1][j]);
                pk.y = pkh(acc[et][2][j], acc[et][3][j]);
                *(uint2*)(Vt + (((size_t)(n * HEADS + l4) * HD + e) * SQ + s)) = pk;
            }
    } else {
        USH* Out = (blockIdx.y == 0) ? Qh : Kh;
        for (int rt = 0; rt < 4; ++rt) {
            int ns = bx * 16 + wv * 4 + rt;
            int n = ns >> 11, s = ns & 2047;
            USH* ob = Out + (((size_t)(n * HEADS) + l4) * SQ + s) * HD;
            for (int et = 0; et < 4; ++et) {
                uint2 pk;
                pk.x = pkh(acc[et][rt][0] * scale, acc[et][rt][1] * scale);
                pk.y = pkh(acc[et][rt][2] * scale, acc[et][rt][3] * scale);
                *(uint2*)(ob + et * 16 + quad * 4) = pk;
            }
        }
    }
}

// stage one 64x64 f16 K tile + one 64x64 V^T tile into (swizzled) LDS buffers.
__device__ __forceinline__ void stage_kv(const USH* __restrict__ Kg,
                                         const USH* __restrict__ Vg,
                                         int kt, USH* Kd, USH* Vd,
                                         int w, int lane)
{
#pragma unroll
    for (int j = 0; j < 2; ++j) {
        int s = (w * 2 + j) * 64 + lane;
        int r = s >> 3, c = (s & 7) ^ (r & 7);
        glds16(Kg + kt * 4096 + r * 64 + c * 8, Kd + s * 8);
    }
#pragma unroll
    for (int j = 0; j < 2; ++j) {
        int s = (w * 2 + j) * 64 + lane;
        int r = s >> 3, c = (s & 7) ^ (r & 7);
        glds16(Vg + r * SQ + kt * 64 + c * 8, Vd + s * 8);
    }
}

// ---------------------------------------------------------------------------
// Flash attention, no-max exp2 softmax. COUNTED-VMCNT pipeline (T3/T4).
// Evidence r0-r3: dur pinned ~70us across occupancy 21/34/36% and conflicts
// 9M/17M (r0-r2, LDS-staged, __syncthreads-per-iter); direct-from-L2 reg
// buffering regressed to 122us (r3: lost the glds DMA + depth-1 prefetch
// latency-bound). Diagnosis: the wall is the per-iter vmcnt(0)+lgkmcnt(0)
// FULL DRAIN that __syncthreads emits (m233: stage+vmcnt+barrier = 72% of
// 2-phase critical path). Fix per T4: triple-buffer K/V (48KB), prefetch
// depth 2, and replace __syncthreads with
//     s_waitcnt vmcnt(4)   (tile kt done; tile kt+1's 4 glds STAY IN FLIGHT
//                           across the barrier -- never drain to 0)
//     raw s_barrier + sched_barrier(0) fence (rule #18).
// Buffer safety: buf (kt+2)%3's readers ran at iter kt-1; their ds_reads
// completed before they arrived at barrier kt, so the DMA overwrite is
// ordered. T5 setprio(1) wraps the MFMA/exp2 cluster (pays once the
// schedule is phase-split, m218b). Wave = 16-key stripe x all 64 q.
// ---------------------------------------------------------------------------
__global__ __launch_bounds__(256, 3) void attn_kernel(
    const USH* __restrict__ Qh, const USH* __restrict__ Kh,
    const USH* __restrict__ Vt, USH* __restrict__ Oh)
{
    __shared__ union {
        struct { USH K[3][4096]; USH V[3][4096]; } s;        // 48 KB
        struct { float Osum[64][68]; float Lsum[64]; } r;    // 17.7 KB
    } lds;

    int t = threadIdx.x, w = t >> 6, lane = t & 63;
    int l4 = lane & 15, quad = lane >> 4;
    int b = blockIdx.x;
    int nh = b & 31;                 // all q-tiles of a head land on one XCD
    int q0 = (b >> 5) * 64;
    const USH* Qg = Qh + ((size_t)nh * SQ + q0) * HD;
    const USH* Kg = Kh + (size_t)nh * SQ * HD;
    const USH* Vg = Vt + (size_t)nh * HD * SQ;

    // Q fragments direct from global (one-time; B-operand layout)
    h8 bq[4][2];
#pragma unroll
    for (int qt = 0; qt < 4; ++qt)
#pragma unroll
        for (int ks = 0; ks < 2; ++ks)
            bq[qt][ks] = *(const h8*)(Qg + (size_t)(qt * 16 + l4) * HD + ks * 32 + quad * 8);

    f4 o[4][4];
#pragma unroll
    for (int dt = 0; dt < 4; ++dt)
#pragma unroll
        for (int qt = 0; qt < 4; ++qt) o[dt][qt] = (f4)(0.0f);
    float lsum[4] = {0.f, 0.f, 0.f, 0.f};

    int key = w * 16 + l4;
    int kslot0 = key * 8 + (quad ^ (key & 7));
    int kslot1 = key * 8 + ((4 + quad) ^ (key & 7));
    int dchunk = w * 2 + (quad >> 1);
    int vbyte  = (quad & 1) * 4;     // USH offset (8 bytes)

    // prologue: stage tiles 0 and 1 (8 glds outstanding per wave)
    stage_kv(Kg, Vg, 0, lds.s.K[0], lds.s.V[0], w, lane);
    stage_kv(Kg, Vg, 1, lds.s.K[1], lds.s.V[1], w, lane);

    int cur = 0;
    for (int kt = 0; kt < SQ / 64; ++kt) {
        // tile kt's 4 glds complete; tile kt+1's remain in flight (counted
        // wait -- the whole point). Last iter: full drain.
        if (kt < SQ / 64 - 2) {
            asm volatile("s_waitcnt vmcnt(4)" ::: "memory");
        } else {
            asm volatile("s_waitcnt vmcnt(0)" ::: "memory");
        }
        __builtin_amdgcn_s_barrier();
        __builtin_amdgcn_sched_barrier(0);

        // issue tile kt+2 into the buffer read at iter kt-1 (safe: its
        // readers' ds_reads completed before they reached this barrier)
        int nb = cur + 2; if (nb >= 3) nb -= 3;
        if (kt + 2 < SQ / 64)
            stage_kv(Kg, Vg, kt + 2, lds.s.K[nb], lds.s.V[nb], w, lane);

        // K fragments for this wave's 16-key stripe
        h8 ak0 = *(const h8*)(lds.s.K[cur] + kslot0 * 8);
        h8 ak1 = *(const h8*)(lds.s.K[cur] + kslot1 * 8);

        // V fragments (A-operand of 16x16x16: A[m=d][k=quad*4+j], 8B)
        h4 av[4];
#pragma unroll
        for (int dt = 0; dt < 4; ++dt) {
            int d = dt * 16 + l4;
            int vs = d * 8 + (dchunk ^ (d & 7));
            av[dt] = *(const h4*)(lds.s.V[cur] + vs * 8 + vbyte);
        }

        __builtin_amdgcn_s_setprio(1);
        // S^T = K Q^T : C[key=quad*4+r][q=l4] -> exp2 -> pack -> O += P V
        h4 p[4];
#pragma unroll
        for (int qt = 0; qt < 4; ++qt) {
            f4 s0 = __builtin_amdgcn_mfma_f32_16x16x32_f16(ak0, bq[qt][0], (f4)(0.0f), 0, 0, 0);
            f4 sc = __builtin_amdgcn_mfma_f32_16x16x32_f16(ak1, bq[qt][1], s0, 0, 0, 0);
            float p0 = __builtin_amdgcn_exp2f(sc[0]);
            float p1 = __builtin_amdgcn_exp2f(sc[1]);
            float p2 = __builtin_amdgcn_exp2f(sc[2]);
            float p3 = __builtin_amdgcn_exp2f(sc[3]);
            lsum[qt] += (p0 + p1) + (p2 + p3);
            uint2 u; u.x = pkh(p0, p1); u.y = pkh(p2, p3);
            p[qt] = __builtin_bit_cast(h4, u);
        }
#pragma unroll
        for (int dt = 0; dt < 4; ++dt)
#pragma unroll
            for (int qt = 0; qt < 4; ++qt)
                o[dt][qt] = __builtin_amdgcn_mfma_f32_16x16x16f16(
                    av[dt], p[qt], o[dt][qt], 0, 0, 0);
        __builtin_amdgcn_s_setprio(0);

        cur = cur + 1 == 3 ? 0 : cur + 1;
    }

    // quad-reduce lsum (quads hold disjoint keys of this wave's stripe)
#pragma unroll
    for (int qt = 0; qt < 4; ++qt) {
        lsum[qt] += __shfl_xor(lsum[qt], 16, 64);
        lsum[qt] += __shfl_xor(lsum[qt], 32, 64);
    }

    // cross-wave O/L reduction through LDS (union reuse)
    __syncthreads();
    for (int ph = 0; ph < 4; ++ph) {
        if (w == ph) {
            for (int dt = 0; dt < 4; ++dt)
                for (int qt = 0; qt < 4; ++qt) {
                    float* dst = &lds.r.Osum[qt * 16 + l4][dt * 16 + quad * 4];
                    f4 val = o[dt][qt];
                    if (ph) val += *(const f4*)dst;
                    *(f4*)dst = val;
                }
            if (quad == 0)
                for (int qt = 0; qt < 4; ++qt) {
                    int qi = qt * 16 + l4;
                    lds.r.Lsum[qi] = ph ? (lds.r.Lsum[qi] + lsum[qt]) : lsum[qt];
                }
        }
        __syncthreads();
    }

    // epilogue: normalize + f16 store
    int n = nh >> 4, h = nh & 15;
    int q = t >> 2, d0 = (t & 3) * 16;
    float inv = 1.0f / lds.r.Lsum[q];
    float vv[16];
#pragma unroll
    for (int i = 0; i < 4; ++i) {
        f4 x = *(const f4*)&lds.r.Osum[q][d0 + i * 4];
        vv[i * 4 + 0] = x[0] * inv; vv[i * 4 + 1] = x[1] * inv;
        vv[i * 4 + 2] = x[2] * inv; vv[i * 4 + 3] = x[3] * inv;
    }
    uint4 ou0, ou1;
    ou0.x = pkh(vv[0], vv[1]);   ou0.y = pkh(vv[2], vv[3]);
    ou0.z = pkh(vv[4], vv[5]);   ou0.w = pkh(vv[6], vv[7]);
    ou1.x = pkh(vv[8], vv[9]);   ou1.y = pkh(vv[10], vv[11]);
    ou1.z = pkh(vv[12], vv[13]); ou1.w = pkh(vv[14], vv[15]);
    USH* ob = Oh + ((size_t)(n * SQ + q0 + q)) * EMB + h * HD + d0;
    *(uint4*)ob = ou0;
    *(uint4*)(ob + 8) = ou1;
}

// ---------------------------------------------------------------------------
// Output GEMM: C[4096][1024] = A[4096][1024] * B[1024][1024]^T (f16 -> fp32)
// BM=BN=64, BK=64 dbuf (32KB), grid 1024 = 4 blocks/CU, 16 waves/CU.
// ---------------------------------------------------------------------------
__global__ __launch_bounds__(256, 4) void gemm_bt(const USH* __restrict__ A,
                                                  const USH* __restrict__ B,
                                                  float* __restrict__ C)
{
    __shared__ __align__(16) USH Al[2][4096];
    __shared__ __align__(16) USH Bl[2][4096];
    int t = threadIdx.x, w = t >> 6, lane = t & 63;
    int l4 = lane & 15, quad = lane >> 4;
    int b = blockIdx.x;
    int m0 = (b & 63) * 64;
    int n0 = (b >> 6) * 64;
    int wm = (w >> 1) * 32, wn = (w & 1) * 32;

    f4 acc[2][2];
    for (int mt = 0; mt < 2; ++mt)
        for (int nt = 0; nt < 2; ++nt) acc[mt][nt] = (f4)(0.0f);

    int aslot[2][2], bslot[2][2];
#pragma unroll
    for (int mt = 0; mt < 2; ++mt)
#pragma unroll
        for (int ks = 0; ks < 2; ++ks) {
            int m = wm + mt * 16 + l4;
            aslot[mt][ks] = m * 8 + ((ks * 4 + quad) ^ (m & 7));
            int nn = wn + mt * 16 + l4;
            bslot[mt][ks] = nn * 8 + ((ks * 4 + quad) ^ (nn & 7));
        }

    // prologue: stage ki=0 into buffer 0
#pragma unroll
    for (int j = 0; j < 2; ++j) {
        int s = (w * 2 + j) * 64 + lane;
        int r = s >> 3, c = (s & 7) ^ (r & 7);
        glds16(A + (size_t)(m0 + r) * 1024 + c * 8, Al[0] + s * 8);
        glds16(B + (size_t)(n0 + r) * 1024 + c * 8, Bl[0] + s * 8);
    }

    for (int ki = 0; ki < 16; ++ki) {
        int cur = ki & 1;
        __syncthreads();
        if (ki + 1 < 16) {
            int k0 = (ki + 1) * 64;
#pragma unroll
            for (int j = 0; j < 2; ++j) {
                int s = (w * 2 + j) * 64 + lane;
                int r = s >> 3, c = (s & 7) ^ (r & 7);
                glds16(A + (size_t)(m0 + r) * 1024 + k0 + c * 8, Al[cur ^ 1] + s * 8);
                glds16(B + (size_t)(n0 + r) * 1024 + k0 + c * 8, Bl[cur ^ 1] + s * 8);
            }
        }

        h8 a[2][2], bf[2][2];
#pragma unroll
        for (int mt = 0; mt < 2; ++mt)
#pragma unroll
            for (int ks = 0; ks < 2; ++ks) {
                a[mt][ks]  = *(const h8*)(Al[cur] + aslot[mt][ks] * 8);
                bf[mt][ks] = *(const h8*)(Bl[cur] + bslot[mt][ks] * 8);
            }
#pragma unroll
        for (int mt = 0; mt < 2; ++mt)
#pragma unroll
            for (int nt = 0; nt < 2; ++nt)
#pragma unroll
                for (int ks = 0; ks < 2; ++ks)
                    acc[mt][nt] = __builtin_amdgcn_mfma_f32_16x16x32_f16(
                        a[mt][ks], bf[nt][ks], acc[mt][nt], 0, 0, 0);
    }

    for (int mt = 0; mt < 2; ++mt)
        for (int nt = 0; nt < 2; ++nt)
            for (int r = 0; r < 4; ++r)
                C[(size_t)(m0 + wm + mt * 16 + quad * 4 + r) * 1024 +
                  (n0 + wn + nt * 16 + l4)] = acc[mt][nt][r];
}

// ---------------------------------------------------------------------------
extern "C" void kernel_launch(void* const* d_in, const int* in_sizes, int n_in,
                              void* d_out, int out_size, void* d_ws, size_t ws_size,
                              hipStream_t stream) {
    const float* k_in = (const float*)d_in[0];
    const float* q_in = (const float*)d_in[1];
    const float* v_in = (const float*)d_in[2];
    const float* Wk   = (const float*)d_in[3];
    const float* Wq   = (const float*)d_in[4];
    const float* Wv   = (const float*)d_in[5];
    const float* Wo   = (const float*)d_in[6];
    float* out = (float*)d_out;

    char* ws = (char*)d_ws;
    USH* Qh  = (USH*)(ws);               //  8 MB [n,h,s,d] f16 (scale folded)
    USH* Kh  = (USH*)(ws + 8388608);     //  8 MB [n,h,s,d]
    USH* Vt  = (USH*)(ws + 16777216);    //  8 MB [n,h,d,s]
    USH* Oh  = (USH*)(ws + 25165824);    //  8 MB [n,s,1024]
    USH* Wob = (USH*)(ws + 33554432);    //  2 MB

    proj_fused<<<dim3(256, 4), dim3(256), 0, stream>>>(
        q_in, k_in, v_in, Wq, Wk, Wv, Wo, Qh, Kh, Vt, Wob);
    attn_kernel<<<dim3(1024), dim3(256), 0, stream>>>(Qh, Kh, Vt, Oh);
    gemm_bt<<<dim3(1024), dim3(256), 0, stream>>>(Oh, Wob, out);
}

// Round 6
// 187.006 us; speedup vs baseline: 1.2888x; 1.0353x over previous
//
#include <hip/hip_runtime.h>

#define SQ   2048
#define HEADS 16
#define HD   64
#define EMB  1024

typedef __attribute__((ext_vector_type(2))) __fp16 h2;
typedef __attribute__((ext_vector_type(4))) __fp16 h4;
typedef __attribute__((ext_vector_type(8))) __fp16 h8;
typedef __attribute__((ext_vector_type(4))) float f4;
typedef unsigned short USH;
typedef unsigned int   UI;

__device__ __forceinline__ UI pkh(float a, float b) {   // pack 2 f16 (RTZ)
    h2 v = __builtin_amdgcn_cvt_pkrtz(a, b);
    return __builtin_bit_cast(UI, v);
}

// async global->LDS, 16B per lane; LDS dest = wave-uniform base + lane*16
__device__ __forceinline__ void glds16(const void* g, void* l) {
    __builtin_amdgcn_global_load_lds(
        (const __attribute__((address_space(1))) unsigned int*)g,
        (__attribute__((address_space(3))) unsigned int*)l, 16, 0, 0);
}

// ---------------------------------------------------------------------------
// Fused Q/K/V per-head projections (y=0,1,2) + Wo fp32->f16 cast (y=3).
// C = W * X^T (operand swap). Q/K written [n,h,s,d]; V written TRANSPOSED
// [n,h,d,s]. Q carries 0.125*log2(e) so attention softmax is a bare exp2.
// Block remap (bx&7)*32+(bx>>3): XCD-major s-chunks (r3, kept).
// ---------------------------------------------------------------------------
__global__ __launch_bounds__(256) void proj_fused(
    const float* __restrict__ q_in, const float* __restrict__ k_in,
    const float* __restrict__ v_in, const float* __restrict__ Wq,
    const float* __restrict__ Wk,   const float* __restrict__ Wv,
    const float* __restrict__ Wo,
    USH* __restrict__ Qh, USH* __restrict__ Kh, USH* __restrict__ Vt,
    USH* __restrict__ Wob)
{
    int t = threadIdx.x;
    if (blockIdx.y == 3) {
        int i = blockIdx.x * 256 + t;
        for (int j = 0; j < 4; ++j) {
            float4 v = ((const float4*)Wo)[i + j * 65536];
            uint2 pk; pk.x = pkh(v.x, v.y); pk.y = pkh(v.z, v.w);
            *(uint2*)(Wob + ((size_t)i + (size_t)j * 65536) * 4) = pk;
        }
        return;
    }
    const float* X = (blockIdx.y == 0) ? q_in : (blockIdx.y == 1) ? k_in : v_in;
    const float* W = (blockIdx.y == 0) ? Wq   : (blockIdx.y == 1) ? Wk   : Wv;
    float scale    = (blockIdx.y == 0) ? 0.18033688011112043f : 1.0f;

    int bx = (blockIdx.x & 7) * 32 + (blockIdx.x >> 3);

    __shared__ __align__(16) USH Xl[256][72];
    __shared__ __align__(16) USH Wl[64][72];

    const float4* Xg = (const float4*)(X + (size_t)bx * 16384);
    for (int j = 0; j < 16; ++j) {
        int f = t + j * 256;
        float4 v = Xg[f];
        int row = f >> 4; int col = (f & 15) << 2;
        uint2 pk; pk.x = pkh(v.x, v.y); pk.y = pkh(v.z, v.w);
        *(uint2*)&Xl[row][col] = pk;
    }
    const float4* Wg = (const float4*)W;
    for (int j = 0; j < 4; ++j) {
        int f = t + j * 256;
        float4 v = Wg[f];
        int row = f >> 4; int col = (f & 15) << 2;
        uint2 pk; pk.x = pkh(v.x, v.y); pk.y = pkh(v.z, v.w);
        *(uint2*)&Wl[row][col] = pk;
    }
    __syncthreads();

    int wv = t >> 6, lane = t & 63, l4 = lane & 15, quad = lane >> 4;

    h8 wf[4][2], xf[4][2];
    for (int et = 0; et < 4; ++et)
        for (int ks = 0; ks < 2; ++ks)
            wf[et][ks] = *(const h8*)&Wl[et * 16 + l4][ks * 32 + quad * 8];
    for (int rt = 0; rt < 4; ++rt)
        for (int ks = 0; ks < 2; ++ks)
            xf[rt][ks] = *(const h8*)&Xl[wv * 64 + rt * 16 + l4][ks * 32 + quad * 8];

    f4 acc[4][4];
    for (int et = 0; et < 4; ++et)
        for (int rt = 0; rt < 4; ++rt) acc[et][rt] = (f4)(0.0f);
    for (int et = 0; et < 4; ++et)
        for (int rt = 0; rt < 4; ++rt)
            for (int ks = 0; ks < 2; ++ks)
                acc[et][rt] = __builtin_amdgcn_mfma_f32_16x16x32_f16(
                    wf[et][ks], xf[rt][ks], acc[et][rt], 0, 0, 0);

    if (blockIdx.y == 2) {
        int ns0 = bx * 16 + wv * 4;
        int n = ns0 >> 11, s = ns0 & 2047;
        for (int et = 0; et < 4; ++et)
            for (int j = 0; j < 4; ++j) {
                int e = et * 16 + quad * 4 + j;
                uint2 pk;
                pk.x = pkh(acc[et][0][j], acc[et][1][j]);
                pk.y = pkh(acc[et][2][j], acc[et][3][j]);
                *(uint2*)(Vt + (((size_t)(n * HEADS + l4) * HD + e) * SQ + s)) = pk;
            }
    } else {
        USH* Out = (blockIdx.y == 0) ? Qh : Kh;
        for (int rt = 0; rt < 4; ++rt) {
            int ns = bx * 16 + wv * 4 + rt;
            int n = ns >> 11, s = ns & 2047;
            USH* ob = Out + (((size_t)(n * HEADS) + l4) * SQ + s) * HD;
            for (int et = 0; et < 4; ++et) {
                uint2 pk;
                pk.x = pkh(acc[et][rt][0] * scale, acc[et][rt][1] * scale);
                pk.y = pkh(acc[et][rt][2] * scale, acc[et][rt][3] * scale);
                *(uint2*)(ob + et * 16 + quad * 4) = pk;
            }
        }
    }
}

// stage one 64x64 f16 K tile (swizzled) into an LDS buffer
__device__ __forceinline__ void stage_k(const USH* __restrict__ Kg,
                                        int kt, USH* Kd, int w, int lane)
{
#pragma unroll
    for (int j = 0; j < 2; ++j) {
        int s = (w * 2 + j) * 64 + lane;
        int r = s >> 3, c = (s & 7) ^ (r & 7);
        glds16(Kg + kt * 4096 + r * 64 + c * 8, Kd + s * 8);
    }
}
// stage one 64x64 f16 V^T tile (swizzled) into an LDS buffer
__device__ __forceinline__ void stage_v(const USH* __restrict__ Vg,
                                        int kt, USH* Vd, int w, int lane)
{
#pragma unroll
    for (int j = 0; j < 2; ++j) {
        int s = (w * 2 + j) * 64 + lane;
        int r = s >> 3, c = (s & 7) ^ (r & 7);
        glds16(Vg + r * SQ + kt * 64 + c * 8, Vd + s * 8);
    }
}

// ---------------------------------------------------------------------------
// Flash attention, no-max exp2 softmax.
// KEY CHANGE (r5, resubmitted after infra failure): PV moved off the legacy
// mfma_f32_16x16x16f16. Evidence: MfmaUtil x dur INVARIANT at ~20.2us across
// r0/r3/r4's different schedules; nominal MFMA work is 6.4us -> the K=16 f16
// shape measures ~21cy/inst (4x the 16x16x32 cost at HALF the FLOPs). Fix:
// PV at K=32 spanning TWO consecutive 64-key tiles -- MFMA's k-dim is just a
// summation index, so slot (quad,j<4)=tile t0 key quad*4+j, (quad,j>=4)=tile
// t1 same key. B = concat(pA,pB) (P regs of two iters, ZERO shuffles);
// A = two 8B V reads at the same swizzled address in two V buffers.
// V is quad-buffered (K double): 48KB LDS, 3 blocks/CU (= r0 effective).
// Loop = 16 x {phase A: QK->pA | phase B: QK->pB + one K=32 PV for both}.
// Skeleton is r0's proven drain-barrier (syncthreads drains glds issued one
// phase earlier); every buffer has >=1 phase + barrier between DMA overwrite
// and last consumed read (re-audited r6). Wave = 16-key stripe x all 64 q.
// ---------------------------------------------------------------------------
__global__ __launch_bounds__(256, 3) void attn_kernel(
    const USH* __restrict__ Qh, const USH* __restrict__ Kh,
    const USH* __restrict__ Vt, USH* __restrict__ Oh)
{
    __shared__ union {
        struct { USH K[2][4096]; USH V[4][4096]; } s;        // 48 KB
        struct { float Osum[64][68]; float Lsum[64]; } r;    // 17.7 KB
    } lds;

    int t = threadIdx.x, w = t >> 6, lane = t & 63;
    int l4 = lane & 15, quad = lane >> 4;
    int b = blockIdx.x;
    int nh = b & 31;                 // all q-tiles of a head land on one XCD
    int q0 = (b >> 5) * 64;
    const USH* Qg = Qh + ((size_t)nh * SQ + q0) * HD;
    const USH* Kg = Kh + (size_t)nh * SQ * HD;
    const USH* Vg = Vt + (size_t)nh * HD * SQ;

    // Q fragments direct from global (one-time; B-operand layout)
    h8 bq[4][2];
#pragma unroll
    for (int qt = 0; qt < 4; ++qt)
#pragma unroll
        for (int ks = 0; ks < 2; ++ks)
            bq[qt][ks] = *(const h8*)(Qg + (size_t)(qt * 16 + l4) * HD + ks * 32 + quad * 8);

    f4 o[4][4];
#pragma unroll
    for (int dt = 0; dt < 4; ++dt)
#pragma unroll
        for (int qt = 0; qt < 4; ++qt) o[dt][qt] = (f4)(0.0f);
    float lsum[4] = {0.f, 0.f, 0.f, 0.f};

    int key = w * 16 + l4;
    int kslot0 = key * 8 + (quad ^ (key & 7));
    int kslot1 = key * 8 + ((4 + quad) ^ (key & 7));
    // V fragment address (same per-lane offset in every V buffer):
    // 8B of V^T[d = dt*16+l4][keys w*16 + quad*4 .. +3]
    int dchunk = w * 2 + (quad >> 1);
    int vbyte  = (quad & 1) * 4;     // USH offset (8 bytes)
    int vs[4];
#pragma unroll
    for (int dt = 0; dt < 4; ++dt) {
        int d = dt * 16 + l4;
        vs[dt] = (d * 8 + (dchunk ^ (d & 7))) * 8 + vbyte;
    }

    // prologue: stage tile 0 (K buf0, V buf0)
    stage_k(Kg, 0, lds.s.K[0], w, lane);
    stage_v(Vg, 0, lds.s.V[0], w, lane);

    uint2 pA[4];
    for (int i = 0; i < 16; ++i) {
        int t0 = 2 * i, t1 = 2 * i + 1;
        USH* Vb0 = lds.s.V[t0 & 3];
        USH* Vb1 = lds.s.V[t1 & 3];

        // ---- phase A: tile t0 -> pA -------------------------------------
        __syncthreads();             // drains glds(t0), issued one phase ago
        stage_k(Kg, t0 + 1, lds.s.K[1], w, lane);
        stage_v(Vg, t0 + 1, Vb1, w, lane);

        {
            h8 ak0 = *(const h8*)(lds.s.K[0] + kslot0 * 8);
            h8 ak1 = *(const h8*)(lds.s.K[0] + kslot1 * 8);
#pragma unroll
            for (int qt = 0; qt < 4; ++qt) {
                f4 s0 = __builtin_amdgcn_mfma_f32_16x16x32_f16(ak0, bq[qt][0], (f4)(0.0f), 0, 0, 0);
                f4 sc = __builtin_amdgcn_mfma_f32_16x16x32_f16(ak1, bq[qt][1], s0, 0, 0, 0);
                float p0 = __builtin_amdgcn_exp2f(sc[0]);
                float p1 = __builtin_amdgcn_exp2f(sc[1]);
                float p2 = __builtin_amdgcn_exp2f(sc[2]);
                float p3 = __builtin_amdgcn_exp2f(sc[3]);
                lsum[qt] += (p0 + p1) + (p2 + p3);
                pA[qt].x = pkh(p0, p1); pA[qt].y = pkh(p2, p3);
            }
        }

        // ---- phase B: tile t1 -> pB, then PV(K=32) over {t0,t1} ---------
        __syncthreads();             // drains glds(t1), issued at phase A
        if (t1 + 1 < 32) {
            stage_k(Kg, t1 + 1, lds.s.K[0], w, lane);
            stage_v(Vg, t1 + 1, lds.s.V[(t1 + 1) & 3], w, lane);
        }

        uint2 pB[4];
        {
            h8 ak0 = *(const h8*)(lds.s.K[1] + kslot0 * 8);
            h8 ak1 = *(const h8*)(lds.s.K[1] + kslot1 * 8);
#pragma unroll
            for (int qt = 0; qt < 4; ++qt) {
                f4 s0 = __builtin_amdgcn_mfma_f32_16x16x32_f16(ak0, bq[qt][0], (f4)(0.0f), 0, 0, 0);
                f4 sc = __builtin_amdgcn_mfma_f32_16x16x32_f16(ak1, bq[qt][1], s0, 0, 0, 0);
                float p0 = __builtin_amdgcn_exp2f(sc[0]);
                float p1 = __builtin_amdgcn_exp2f(sc[1]);
                float p2 = __builtin_amdgcn_exp2f(sc[2]);
                float p3 = __builtin_amdgcn_exp2f(sc[3]);
                lsum[qt] += (p0 + p1) + (p2 + p3);
                pB[qt].x = pkh(p0, p1); pB[qt].y = pkh(p2, p3);
            }
        }

        // V fragments: lo 8B from tile t0's buffer, hi 8B from tile t1's
        h8 av8[4];
#pragma unroll
        for (int dt = 0; dt < 4; ++dt) {
            uint2 lo = *(const uint2*)(Vb0 + vs[dt]);
            uint2 hi = *(const uint2*)(Vb1 + vs[dt]);
            uint4 u; u.x = lo.x; u.y = lo.y; u.z = hi.x; u.w = hi.y;
            av8[dt] = __builtin_bit_cast(h8, u);
        }

        // O += P V, one full-rate K=32 MFMA per (dt,qt) covering both tiles
#pragma unroll
        for (int dt = 0; dt < 4; ++dt)
#pragma unroll
            for (int qt = 0; qt < 4; ++qt) {
                uint4 u; u.x = pA[qt].x; u.y = pA[qt].y;
                u.z = pB[qt].x; u.w = pB[qt].y;
                h8 pp = __builtin_bit_cast(h8, u);
                o[dt][qt] = __builtin_amdgcn_mfma_f32_16x16x32_f16(
                    av8[dt], pp, o[dt][qt], 0, 0, 0);
            }
    }

    // quad-reduce lsum (quads hold disjoint keys of this wave's stripe)
#pragma unroll
    for (int qt = 0; qt < 4; ++qt) {
        lsum[qt] += __shfl_xor(lsum[qt], 16, 64);
        lsum[qt] += __shfl_xor(lsum[qt], 32, 64);
    }

    // cross-wave O/L reduction through LDS (union reuse)
    __syncthreads();
    for (int ph = 0; ph < 4; ++ph) {
        if (w == ph) {
            for (int dt = 0; dt < 4; ++dt)
                for (int qt = 0; qt < 4; ++qt) {
                    float* dst = &lds.r.Osum[qt * 16 + l4][dt * 16 + quad * 4];
                    f4 val = o[dt][qt];
                    if (ph) val += *(const f4*)dst;
                    *(f4*)dst = val;
                }
            if (quad == 0)
                for (int qt = 0; qt < 4; ++qt) {
                    int qi = qt * 16 + l4;
                    lds.r.Lsum[qi] = ph ? (lds.r.Lsum[qi] + lsum[qt]) : lsum[qt];
                }
        }
        __syncthreads();
    }

    // epilogue: normalize + f16 store
    int n = nh >> 4, h = nh & 15;
    int q = t >> 2, d0 = (t & 3) * 16;
    float inv = 1.0f / lds.r.Lsum[q];
    float vv[16];
#pragma unroll
    for (int i = 0; i < 4; ++i) {
        f4 x = *(const f4*)&lds.r.Osum[q][d0 + i * 4];
        vv[i * 4 + 0] = x[0] * inv; vv[i * 4 + 1] = x[1] * inv;
        vv[i * 4 + 2] = x[2] * inv; vv[i * 4 + 3] = x[3] * inv;
    }
    uint4 ou0, ou1;
    ou0.x = pkh(vv[0], vv[1]);   ou0.y = pkh(vv[2], vv[3]);
    ou0.z = pkh(vv[4], vv[5]);   ou0.w = pkh(vv[6], vv[7]);
    ou1.x = pkh(vv[8], vv[9]);   ou1.y = pkh(vv[10], vv[11]);
    ou1.z = pkh(vv[12], vv[13]); ou1.w = pkh(vv[14], vv[15]);
    USH* ob = Oh + ((size_t)(n * SQ + q0 + q)) * EMB + h * HD + d0;
    *(uint4*)ob = ou0;
    *(uint4*)(ob + 8) = ou1;
}

// ---------------------------------------------------------------------------
// Output GEMM: C[4096][1024] = A[4096][1024] * B[1024][1024]^T (f16 -> fp32)
// BM=BN=64, BK=64 dbuf (32KB), grid 1024 = 4 blocks/CU, 16 waves/CU.
// ---------------------------------------------------------------------------
__global__ __launch_bounds__(256, 4) void gemm_bt(const USH* __restrict__ A,
                                                  const USH* __restrict__ B,
                                                  float* __restrict__ C)
{
    __shared__ __align__(16) USH Al[2][4096];
    __shared__ __align__(16) USH Bl[2][4096];
    int t = threadIdx.x, w = t >> 6, lane = t & 63;
    int l4 = lane & 15, quad = lane >> 4;
    int b = blockIdx.x;
    int m0 = (b & 63) * 64;
    int n0 = (b >> 6) * 64;
    int wm = (w >> 1) * 32, wn = (w & 1) * 32;

    f4 acc[2][2];
    for (int mt = 0; mt < 2; ++mt)
        for (int nt = 0; nt < 2; ++nt) acc[mt][nt] = (f4)(0.0f);

    int aslot[2][2], bslot[2][2];
#pragma unroll
    for (int mt = 0; mt < 2; ++mt)
#pragma unroll
        for (int ks = 0; ks < 2; ++ks) {
            int m = wm + mt * 16 + l4;
            aslot[mt][ks] = m * 8 + ((ks * 4 + quad) ^ (m & 7));
            int nn = wn + mt * 16 + l4;
            bslot[mt][ks] = nn * 8 + ((ks * 4 + quad) ^ (nn & 7));
        }

    // prologue: stage ki=0 into buffer 0
#pragma unroll
    for (int j = 0; j < 2; ++j) {
        int s = (w * 2 + j) * 64 + lane;
        int r = s >> 3, c = (s & 7) ^ (r & 7);
        glds16(A + (size_t)(m0 + r) * 1024 + c * 8, Al[0] + s * 8);
        glds16(B + (size_t)(n0 + r) * 1024 + c * 8, Bl[0] + s * 8);
    }

    for (int ki = 0; ki < 16; ++ki) {
        int cur = ki & 1;
        __syncthreads();
        if (ki + 1 < 16) {
            int k0 = (ki + 1) * 64;
#pragma unroll
            for (int j = 0; j < 2; ++j) {
                int s = (w * 2 + j) * 64 + lane;
                int r = s >> 3, c = (s & 7) ^ (r & 7);
                glds16(A + (size_t)(m0 + r) * 1024 + k0 + c * 8, Al[cur ^ 1] + s * 8);
                glds16(B + (size_t)(n0 + r) * 1024 + k0 + c * 8, Bl[cur ^ 1] + s * 8);
            }
        }

        h8 a[2][2], bf[2][2];
#pragma unroll
        for (int mt = 0; mt < 2; ++mt)
#pragma unroll
            for (int ks = 0; ks < 2; ++ks) {
                a[mt][ks]  = *(const h8*)(Al[cur] + aslot[mt][ks] * 8);
                bf[mt][ks] = *(const h8*)(Bl[cur] + bslot[mt][ks] * 8);
            }
#pragma unroll
        for (int mt = 0; mt < 2; ++mt)
#pragma unroll
            for (int nt = 0; nt < 2; ++nt)
#pragma unroll
                for (int ks = 0; ks < 2; ++ks)
                    acc[mt][nt] = __builtin_amdgcn_mfma_f32_16x16x32_f16(
                        a[mt][ks], bf[nt][ks], acc[mt][nt], 0, 0, 0);
    }

    for (int mt = 0; mt < 2; ++mt)
        for (int nt = 0; nt < 2; ++nt)
            for (int r = 0; r < 4; ++r)
                C[(size_t)(m0 + wm + mt * 16 + quad * 4 + r) * 1024 +
                  (n0 + wn + nt * 16 + l4)] = acc[mt][nt][r];
}

// ---------------------------------------------------------------------------
extern "C" void kernel_launch(void* const* d_in, const int* in_sizes, int n_in,
                              void* d_out, int out_size, void* d_ws, size_t ws_size,
                              hipStream_t stream) {
    const float* k_in = (const float*)d_in[0];
    const float* q_in = (const float*)d_in[1];
    const float* v_in = (const float*)d_in[2];
    const float* Wk   = (const float*)d_in[3];
    const float* Wq   = (const float*)d_in[4];
    const float* Wv   = (const float*)d_in[5];
    const float* Wo   = (const float*)d_in[6];
    float* out = (float*)d_out;

    char* ws = (char*)d_ws;
    USH* Qh  = (USH*)(ws);               //  8 MB [n,h,s,d] f16 (scale folded)
    USH* Kh  = (USH*)(ws + 8388608);     //  8 MB [n,h,s,d]
    USH* Vt  = (USH*)(ws + 16777216);    //  8 MB [n,h,d,s]
    USH* Oh  = (USH*)(ws + 25165824);    //  8 MB [n,s,1024]
    USH* Wob = (USH*)(ws + 33554432);    //  2 MB

    proj_fused<<<dim3(256, 4), dim3(256), 0, stream>>>(
        q_in, k_in, v_in, Wq, Wk, Wv, Wo, Qh, Kh, Vt, Wob);
    attn_kernel<<<dim3(1024), dim3(256), 0, stream>>>(Qh, Kh, Vt, Oh);
    gemm_bt<<<dim3(1024), dim3(256), 0, stream>>>(Oh, Wob, out);
}